// Round 1
// 1514.046 us; speedup vs baseline: 1.2531x; 1.2531x over previous
//
#include <hip/hip_runtime.h>

#define SEQ   512
#define BATCH 64
#define DIM   512

typedef float  f32x4 __attribute__((ext_vector_type(4)));
typedef short  s16x8 __attribute__((ext_vector_type(8)));
typedef __bf16 bf16x2 __attribute__((ext_vector_type(2)));

__device__ __forceinline__ float bits2f(unsigned u) {
  union { unsigned u; float f; } v; v.u = u; return v.f;
}
__device__ __forceinline__ float bf2f(unsigned short h) { return bits2f((unsigned)h << 16); }
__device__ __forceinline__ float bflo(unsigned u) { return bits2f(u << 16); }
__device__ __forceinline__ float bfhi(unsigned u) { return bits2f(u & 0xFFFF0000u); }
__device__ __forceinline__ unsigned short f2bf(float f) {
  union { float f; unsigned u; } v; v.f = f;
  unsigned r = v.u + 0x7FFFu + ((v.u >> 16) & 1u);
  return (unsigned short)(r >> 16);
}
__device__ __forceinline__ unsigned packbf(float lo, float hi) {
  return (unsigned)f2bf(lo) | ((unsigned)f2bf(hi) << 16);
}
__device__ __forceinline__ float sigm(float x) { return 1.0f / (1.0f + __expf(-x)); }

// dot of two bf16 pairs accumulated into f32.  w/h pair layout: lo16 = even k,
// hi16 = odd k.
__device__ __forceinline__ float dot2(unsigned w, unsigned h, float acc) {
#if __has_builtin(__builtin_amdgcn_fdot2_f32_bf16)
  return __builtin_amdgcn_fdot2_f32_bf16(__builtin_bit_cast(bf16x2, w),
                                         __builtin_bit_cast(bf16x2, h), acc, false);
#else
  return acc + bflo(w) * bflo(h) + bfhi(w) * bfhi(h);
#endif
}

// LDS-only barrier: waits LDS ops, does NOT drain vmcnt — global stores and
// prefetch loads stay in flight across it (HK / 8-phase pattern).
__device__ __forceinline__ void bar_lds() {
  asm volatile("s_waitcnt lgkmcnt(0)" ::: "memory");
  __builtin_amdgcn_s_barrier();
  asm volatile("" ::: "memory");
}

// ---------------------------------------------------------------------------
// Kernel 1: cast/pack weights.
//  mode 1: fp32 512x512 -> bf16 transposed  (WbT[n][k] = W[k][n])
//  mode 3: Crpk:  [k2<64][j<m]   = pack(Cr[iN+2k2][j],  Cr[iN+2k2+1][j])
//  mode 4: Chpk:  [k2<m/2][j<128]= pack(Ch[2k2][j],     Ch[2k2+1][j])
//  mode 5: Czpk:  [k2<64][j<128] = pack(Cz[iN+2k2][j],  Cz[iN+2k2+1][j])
//  mode 6: Bcat:  bf16 [nrow<m+128][k<iN]: nrow<m -> Cr[k][nrow], else Cz[k][nrow-m]
// ---------------------------------------------------------------------------
#define NJOBS 18
struct CastJobs {
  const float* src[NJOBS];
  const float* src2[NJOBS];
  void*        dst[NJOBS];
  int          n[NJOBS];
  int          mode[NJOBS];
  int          m[NJOBS];
  int          iN[NJOBS];
};

__global__ __launch_bounds__(256) void cast_kernel(CastJobs jobs) {
  int gsz = gridDim.x * blockDim.x;
  int gid = blockIdx.x * blockDim.x + threadIdx.x;
  for (int j = 0; j < NJOBS; ++j) {
    int n = jobs.n[j], mode = jobs.mode[j];
    int m = jobs.m[j], iN = jobs.iN[j];
    const float* s = jobs.src[j];
    if (mode == 1) {
      unsigned short* d = (unsigned short*)jobs.dst[j];
      for (int i = gid; i < n; i += gsz) {
        int k = i >> 9, nn = i & 511;
        d[nn * 512 + k] = f2bf(s[i]);
      }
    } else if (mode == 3) {
      unsigned* d = (unsigned*)jobs.dst[j];
      for (int i = gid; i < n; i += gsz) {
        int k2 = i / m, jj = i - k2 * m;
        d[i] = packbf(s[(iN + 2 * k2) * m + jj], s[(iN + 2 * k2 + 1) * m + jj]);
      }
    } else if (mode == 4) {
      unsigned* d = (unsigned*)jobs.dst[j];
      for (int i = gid; i < n; i += gsz) {
        int k2 = i >> 7, jj = i & 127;
        d[i] = packbf(s[(2 * k2) * 128 + jj], s[(2 * k2 + 1) * 128 + jj]);
      }
    } else if (mode == 5) {
      unsigned* d = (unsigned*)jobs.dst[j];
      for (int i = gid; i < n; i += gsz) {
        int k2 = i >> 7, jj = i & 127;
        d[i] = packbf(s[(iN + 2 * k2) * 128 + jj], s[(iN + 2 * k2 + 1) * 128 + jj]);
      }
    } else if (mode == 6) {
      const float* s2 = jobs.src2[j];
      unsigned short* d = (unsigned short*)jobs.dst[j];
      for (int i = gid; i < n; i += gsz) {
        int nrow = i / iN, k = i - nrow * iN;
        float v = (nrow < m) ? s[k * m + nrow] : s2[k * 128 + (nrow - m)];
        d[i] = f2bf(v);
      }
    }
  }
}

// ---------------------------------------------------------------------------
// Kernel 2: projection GEMM (bf16 MFMA) — validated in R1.
// ---------------------------------------------------------------------------
__global__ __launch_bounds__(256) void proj_kernel(
    const float* __restrict__ x,
    const unsigned short* __restrict__ WbT,
    const float* __restrict__ bias0, const float* __restrict__ bias1,
    const float* __restrict__ bias2,
    unsigned short* __restrict__ p0, unsigned short* __restrict__ p1,
    unsigned short* __restrict__ p2)
{
  __shared__ __align__(16) unsigned short aS[64 * 40];
  __shared__ __align__(16) unsigned short bS[128 * 40];

  int bx = blockIdx.x;
  int nt = bx % 12, t = bx / 12;
  int wsel = nt >> 2, ncol0 = (nt & 3) * 128;
  const float* bias = (wsel == 0) ? bias0 : (wsel == 1 ? bias1 : bias2);
  unsigned short* pout = (wsel == 0) ? p0 : (wsel == 1 ? p1 : p2);

  int tid = threadIdx.x;
  int wv = tid >> 6, lane = tid & 63;
  int lq = lane & 15, quad = lane >> 4;

  f32x4 acc[8];
#pragma unroll
  for (int s = 0; s < 8; ++s) acc[s] = (f32x4){0.f, 0.f, 0.f, 0.f};

  int arow = tid >> 2, ak0 = (tid & 3) * 8;
  const float* asrc0 = x + ((size_t)arow * SEQ + t) * DIM + ak0;
  int brow = tid >> 1, bk0 = (tid & 1) * 16;
  const unsigned short* bsrc0 =
      WbT + ((size_t)(wsel * 512 + ncol0 + brow)) * 512 + bk0;

  for (int kk = 0; kk < 16; ++kk) {
    const float* asrc = asrc0 + kk * 32;
    float4 f0 = *(const float4*)(asrc);
    float4 f1 = *(const float4*)(asrc + 4);
    uint4 av;
    av.x = packbf(f0.x, f0.y);
    av.y = packbf(f0.z, f0.w);
    av.z = packbf(f1.x, f1.y);
    av.w = packbf(f1.z, f1.w);
    *(uint4*)(aS + arow * 40 + ak0) = av;
    const unsigned short* bsrc = bsrc0 + kk * 32;
    *(uint4*)(bS + brow * 40 + bk0)     = *(const uint4*)(bsrc);
    *(uint4*)(bS + brow * 40 + bk0 + 8) = *(const uint4*)(bsrc + 8);
    __syncthreads();

    s16x8 af = *(const s16x8*)(aS + (wv * 16 + lq) * 40 + quad * 8);
#pragma unroll
    for (int s = 0; s < 8; ++s) {
      s16x8 bf = *(const s16x8*)(bS + (s * 16 + lq) * 40 + quad * 8);
      acc[s] = __builtin_amdgcn_mfma_f32_16x16x32_bf16(af, bf, acc[s], 0, 0, 0);
    }
    __syncthreads();
  }

#pragma unroll
  for (int s = 0; s < 8; ++s) {
    int col = ncol0 + s * 16 + lq;
    float bv = bias[col];
#pragma unroll
    for (int v = 0; v < 4; ++v) {
      int b = wv * 16 + quad * 4 + v;
      pout[((size_t)(t * BATCH + b)) * DIM + col] = f2bf(acc[s][v] + bv);
    }
  }
}

// ---------------------------------------------------------------------------
// Kernel 3: base GEMM for block I (I=1..3):
// base[(n*64+b)][c] = sum_{k<iN} out[b][n*2^I - 1][k] * Bcat[c][k]   (bf16 out)
// where Bcat rows: c<m -> Cr_I[:,c], c>=m -> Cz_I[:,c-m].  n=0 rows -> 0.
// ---------------------------------------------------------------------------
template<int I>
__global__ __launch_bounds__(256) void base_gemm(
    const float* __restrict__ outp,
    const unsigned short* __restrict__ Bcat,
    unsigned short* __restrict__ baseO)
{
  constexpr int KI  = 4 * I;      // K/32
  constexpr int K   = 128 * I;    // = iN
  constexpr int NT  = I + 2;      // n-tiles of 128
  constexpr int NW  = NT * 128;   // m + 128
  constexpr int PER = 1 << I;

  __shared__ __align__(16) unsigned short aS[64 * 40];
  __shared__ __align__(16) unsigned short bS[128 * 40];

  int bx = blockIdx.x;
  int nt = bx % NT, n = bx / NT;
  int ncol0 = nt * 128;

  int tid = threadIdx.x;
  int wv = tid >> 6, lane = tid & 63;
  int lq = lane & 15, quad = lane >> 4;

  f32x4 acc[8];
#pragma unroll
  for (int s = 0; s < 8; ++s) acc[s] = (f32x4){0.f, 0.f, 0.f, 0.f};

  int arow = tid >> 2, ak0 = (tid & 3) * 8;
  const float* asrc0 = outp + ((size_t)arow * SEQ + (n * PER - 1)) * DIM + ak0;
  int brow = tid >> 1, bk0 = (tid & 1) * 16;
  const unsigned short* bsrc0 = Bcat + (size_t)(ncol0 + brow) * K + bk0;

  for (int kk = 0; kk < KI; ++kk) {
    uint4 av;
    if (n > 0) {
      const float* asrc = asrc0 + kk * 32;
      float4 f0 = *(const float4*)(asrc);
      float4 f1 = *(const float4*)(asrc + 4);
      av.x = packbf(f0.x, f0.y);
      av.y = packbf(f0.z, f0.w);
      av.z = packbf(f1.x, f1.y);
      av.w = packbf(f1.z, f1.w);
    } else {
      av = (uint4){0u, 0u, 0u, 0u};
    }
    *(uint4*)(aS + arow * 40 + ak0) = av;
    const unsigned short* bsrc = bsrc0 + kk * 32;
    *(uint4*)(bS + brow * 40 + bk0)     = *(const uint4*)(bsrc);
    *(uint4*)(bS + brow * 40 + bk0 + 8) = *(const uint4*)(bsrc + 8);
    __syncthreads();

    s16x8 af = *(const s16x8*)(aS + (wv * 16 + lq) * 40 + quad * 8);
#pragma unroll
    for (int s = 0; s < 8; ++s) {
      s16x8 bf = *(const s16x8*)(bS + (s * 16 + lq) * 40 + quad * 8);
      acc[s] = __builtin_amdgcn_mfma_f32_16x16x32_bf16(af, bf, acc[s], 0, 0, 0);
    }
    __syncthreads();
  }

#pragma unroll
  for (int s = 0; s < 8; ++s) {
    int col = ncol0 + s * 16 + lq;
#pragma unroll
    for (int v = 0; v < 4; ++v) {
      int bb = wv * 16 + quad * 4 + v;
      baseO[(size_t)(n * 64 + bb) * NW + col] = f2bf(acc[s][v]);
    }
  }
}

// ---------------------------------------------------------------------------
// Kernel 4: per-block scan phase, latency-optimized.
//   * 2 raw LDS-only barriers per timestep (no vmcnt drain: out-stores and
//     prefetch loads stay in flight across barriers).
//   * All global inputs (pr/pz/px/base/prev) prefetched 1 iteration ahead.
//   * u-pack and k-split reductions via in-wave shfl_xor (no uF/part/zS LDS).
//   * I>=1: 512 threads, 4-way k-split -> no VGPR spills (I=3 was 320 regs).
// Thread roles (t = tid):
//   r-gate : thread t owns column t  (t < min(M,TPB)), 64 packed k-pairs.
//   z-gate : lane-group (jh = t/SPL, q = t%SPL) splits col jh's 64 pairs.
//   h-gate : same lane-group splits col jh's M/2 pairs; shfl_xor reduce.
// ---------------------------------------------------------------------------
template<int I, int TPB>
__global__ __launch_bounds__(TPB, 1) void scan_phase(
    const unsigned short* __restrict__ px,
    const unsigned short* __restrict__ pr,
    const unsigned short* __restrict__ pz,
    const unsigned* __restrict__ crpk,
    const unsigned* __restrict__ czpk,
    const unsigned* __restrict__ chpk,
    const unsigned short* __restrict__ base,
    float* __restrict__ out)
{
  constexpr int M   = (I + 1) * 128;
  constexpr int IN  = I * 128;
  constexpr int PER = 1 << I;
  constexpr int U   = 512 >> I;
  constexpr int NW  = M + 128;
  constexpr int HKP = M / 2;             // h k-pairs (full u length)
  constexpr int SPL = (I == 0) ? 2 : 4;  // k-split ways per output col
  constexpr int HT  = HKP / SPL;         // h k-pairs per thread
  constexpr int ZT  = 64 / SPL;          // z k-pairs per thread
  constexpr int RTH = (M < TPB) ? M : TPB;

  __shared__ __align__(16) float    hS[128];
  __shared__ __align__(16) unsigned hPk[64];
  __shared__ __align__(16) unsigned uPk[HKP];

  const int b  = blockIdx.x;
  const int t  = threadIdx.x;
  const int jh = t / SPL;   // h/z column (0..127)
  const int q  = t % SPL;   // k-split index within lane group
  const bool hasR = (t < RTH);
  const int col0 = t;

  // ---- weights -> registers (loop-invariant)
  unsigned wr0[64];
  if (hasR) {
#pragma unroll
    for (int k2 = 0; k2 < 64; ++k2) wr0[k2] = crpk[k2 * M + col0];
  }
  unsigned wz[ZT];
#pragma unroll
  for (int k2 = 0; k2 < ZT; ++k2) wz[k2] = czpk[(q * ZT + k2) * 128 + jh];
  unsigned wh[HT];
#pragma unroll
  for (int k2 = 0; k2 < HT; ++k2) wh[k2] = chpk[(q * HT + k2) * 128 + jh];

  if (t < 128) hS[t] = 0.f;
  if (t < 64)  hPk[t] = 0u;
  float vprev = 0.f;   // this lane-group's h value at previous step

  // ---- prefetch iteration 0 inputs
  unsigned short f_pr = 0, f_pz = 0, f_px = 0, f_br = 0, f_bz = 0;
  float f_pv = 0.f;
  {
    f_pz = (pz + (size_t)b * DIM)[IN + jh];
    f_px = (px + (size_t)b * DIM)[IN + jh];
    if (hasR) f_pr = (pr + (size_t)b * DIM)[col0];
    if constexpr (I > 0) {
      const unsigned short* baseR = base + (size_t)b * NW;
      if (hasR) f_br = baseR[col0];
      f_bz = baseR[M + jh];
    }
  }

  bar_lds();  // hS/hPk zeros visible

  for (int n = 0; n < U; ++n) {
    const int s = n * PER;
    const unsigned short c_pr = f_pr, c_pz = f_pz, c_px = f_px;
    const unsigned short c_br = f_br, c_bz = f_bz;
    const float c_pv = f_pv;

    // ---- issue prefetch for iteration n+1 (clamped; unused on last iter)
    {
      const int n2 = (n + 1 < U) ? (n + 1) : n;
      const int s2 = n2 * PER;
      f_pz = (pz + ((size_t)(s2 * BATCH + b)) * DIM)[IN + jh];
      f_px = (px + ((size_t)(s2 * BATCH + b)) * DIM)[IN + jh];
      if (hasR) f_pr = (pr + ((size_t)(s2 * BATCH + b)) * DIM)[col0];
      if constexpr (I > 0) {
        const unsigned short* baseR = base + (size_t)(n2 * 64 + b) * NW;
        if (hasR) f_br = baseR[col0];
        f_bz = baseR[M + jh];
        if (hasR && col0 < IN)
          f_pv = (out + ((size_t)b * SEQ + (s2 - 1)) * DIM)[col0];
      }
    }

    // ---------------- seg1: z and r gates from hPk ----------------
    float az0 = 0.f, az1 = 0.f;
#pragma unroll
    for (int k2 = 0; k2 < ZT; k2 += 2) {
      az0 = dot2(wz[k2],     hPk[q * ZT + k2],     az0);
      az1 = dot2(wz[k2 + 1], hPk[q * ZT + k2 + 1], az1);
    }
    float az = az0 + az1;
    az += __shfl_xor(az, 1);
    if constexpr (SPL == 4) az += __shfl_xor(az, 2);
    float zpre = bf2f(c_pz) + az;
    if constexpr (I > 0) zpre += bf2f(c_bz);
    const float zg = sigm(zpre);

    float u = 0.f;
    if (hasR) {
      float a0 = 0.f, a1 = 0.f, a2 = 0.f, a3 = 0.f;
#pragma unroll
      for (int k2 = 0; k2 < 64; k2 += 4) {
        a0 = dot2(wr0[k2],     hPk[k2],     a0);
        a1 = dot2(wr0[k2 + 1], hPk[k2 + 1], a1);
        a2 = dot2(wr0[k2 + 2], hPk[k2 + 2], a2);
        a3 = dot2(wr0[k2 + 3], hPk[k2 + 3], a3);
      }
      float ar = bf2f(c_pr) + (a0 + a1) + (a2 + a3);
      if constexpr (I > 0) ar += bf2f(c_br);
      const float r = sigm(ar);
      float hp;
      if constexpr (I == 0) hp = hS[col0];
      else hp = (col0 >= IN) ? hS[col0 - IN] : c_pv;
      u = r * hp;
    }
    const float uo = __shfl_xor(u, 1);
    if (hasR && !(t & 1)) uPk[t >> 1] = packbf(u, uo);

    bar_lds();  // A: uPk ready; seg1's hS/hPk reads retired

    // ---------------- seg3: candidate state + blend ----------------
    float ah0 = 0.f, ah1 = 0.f, ah2 = 0.f, ah3 = 0.f;
    {
      const int o = q * HT;
#pragma unroll
      for (int k2 = 0; k2 < HT; k2 += 4) {
        ah0 = dot2(wh[k2],     uPk[o + k2],     ah0);
        ah1 = dot2(wh[k2 + 1], uPk[o + k2 + 1], ah1);
        ah2 = dot2(wh[k2 + 2], uPk[o + k2 + 2], ah2);
        ah3 = dot2(wh[k2 + 3], uPk[o + k2 + 3], ah3);
      }
    }
    float ah = (ah0 + ah1) + (ah2 + ah3);
    ah += __shfl_xor(ah, 1);
    if constexpr (SPL == 4) ah += __shfl_xor(ah, 2);
    const float hnew = sigm(ah + bf2f(c_px));
    const float v = zg * hnew + (1.f - zg) * vprev;
    vprev = v;

    if (q == 0) hS[jh] = v;
    const float vp = __shfl_xor(v, SPL);              // partner col's v
    if ((t & (2 * SPL - 1)) == 0) hPk[t / (2 * SPL)] = packbf(v, vp);

    // global out store: PER replicated rows, no vmcnt drain at the barrier
    float* orow = out + ((size_t)b * SEQ + s) * DIM + IN + jh;
#pragma unroll
    for (int p = q; p < PER; p += SPL) orow[p * DIM] = v;

    bar_lds();  // E: hS/hPk ready for next iteration
  }
}

// ---------------------------------------------------------------------------
// Host launcher
// ---------------------------------------------------------------------------
extern "C" void kernel_launch(void* const* d_in, const int* in_sizes, int n_in,
                              void* d_out, int out_size, void* d_ws, size_t ws_size,
                              hipStream_t stream) {
  (void)in_sizes; (void)n_in; (void)out_size; (void)ws_size;

  const float* x  = (const float*)d_in[0];
  const float* W  = (const float*)d_in[1];
  const float* bb = (const float*)d_in[2];
  const float* Wr = (const float*)d_in[3];
  const float* br = (const float*)d_in[4];
  const float* Wz = (const float*)d_in[5];
  const float* bz = (const float*)d_in[6];
  const float* ch_[4]; const float* cr_[4]; const float* cz_[4];
  for (int i = 0; i < 4; ++i) {
    ch_[i] = (const float*)d_in[7 + 3 * i];
    cr_[i] = (const float*)d_in[8 + 3 * i];
    cz_[i] = (const float*)d_in[9 + 3 * i];
  }

  char* ws = (char*)d_ws;
  size_t off = 0;
  auto alloc = [&](size_t bytes) -> void* {
    void* p = ws + off;
    off += (bytes + 255) & ~(size_t)255;
    return p;
  };

  unsigned short* WbT = (unsigned short*)alloc(3ull * 512 * 512 * 2);
  unsigned* Crpk[4]; unsigned* Chpk[4]; unsigned* Czpk[4];
  unsigned short* Bcat[4] = {nullptr, nullptr, nullptr, nullptr};
  for (int i = 0; i < 4; ++i) {
    int m = (i + 1) * 128;
    Crpk[i] = (unsigned*)alloc((size_t)64 * m * 4);
    Chpk[i] = (unsigned*)alloc((size_t)(m / 2) * 128 * 4);
    Czpk[i] = (unsigned*)alloc((size_t)64 * 128 * 4);
  }
  for (int i = 1; i < 4; ++i) {
    int m = (i + 1) * 128, iN = i * 128;
    Bcat[i] = (unsigned short*)alloc((size_t)(m + 128) * iN * 2);
  }
  unsigned short* p0 = (unsigned short*)alloc((size_t)SEQ * BATCH * DIM * 2);
  unsigned short* p1 = (unsigned short*)alloc((size_t)SEQ * BATCH * DIM * 2);
  unsigned short* p2 = (unsigned short*)alloc((size_t)SEQ * BATCH * DIM * 2);
  unsigned short* baseB = (unsigned short*)alloc((size_t)16384 * 384 * 2);  // max of G1..G3
  // total ~117 MB

  // ---- cast/pack jobs
  CastJobs jobs{};
  int jn = 0;
  const float* wsrc[3] = {W, Wr, Wz};
  for (int j = 0; j < 3; ++j) {
    jobs.src[jn] = wsrc[j]; jobs.dst[jn] = WbT + (size_t)j * 512 * 512;
    jobs.n[jn] = 512 * 512; jobs.mode[jn] = 1; jobs.m[jn] = 512; jobs.iN[jn] = 0; jn++;
  }
  for (int i = 0; i < 4; ++i) {
    int m = (i + 1) * 128, iN = i * 128;
    jobs.src[jn] = cr_[i]; jobs.dst[jn] = Crpk[i];
    jobs.n[jn] = 64 * m; jobs.mode[jn] = 3; jobs.m[jn] = m; jobs.iN[jn] = iN; jn++;
    jobs.src[jn] = ch_[i]; jobs.dst[jn] = Chpk[i];
    jobs.n[jn] = (m / 2) * 128; jobs.mode[jn] = 4; jobs.m[jn] = m; jobs.iN[jn] = iN; jn++;
    jobs.src[jn] = cz_[i]; jobs.dst[jn] = Czpk[i];
    jobs.n[jn] = 64 * 128; jobs.mode[jn] = 5; jobs.m[jn] = m; jobs.iN[jn] = iN; jn++;
  }
  for (int i = 1; i < 4; ++i) {
    int m = (i + 1) * 128, iN = i * 128;
    jobs.src[jn] = cr_[i]; jobs.src2[jn] = cz_[i]; jobs.dst[jn] = Bcat[i];
    jobs.n[jn] = (m + 128) * iN; jobs.mode[jn] = 6; jobs.m[jn] = m; jobs.iN[jn] = iN; jn++;
  }
  cast_kernel<<<256, 256, 0, stream>>>(jobs);

  // ---- projections
  proj_kernel<<<SEQ * 12, 256, 0, stream>>>(x, WbT, bb, br, bz, p0, p1, p2);

  float* outp = (float*)d_out;

  // ---- cascade: B0 -> G1 -> B1 -> G2 -> B2 -> G3 -> B3
  scan_phase<0, 256><<<64, 256, 0, stream>>>(p0, p1, p2, Crpk[0], Czpk[0],
                                             Chpk[0], nullptr, outp);
  base_gemm<1><<<256 * 3, 256, 0, stream>>>(outp, Bcat[1], baseB);
  scan_phase<1, 512><<<64, 512, 0, stream>>>(p0, p1, p2, Crpk[1], Czpk[1],
                                             Chpk[1], baseB, outp);
  base_gemm<2><<<128 * 4, 256, 0, stream>>>(outp, Bcat[2], baseB);
  scan_phase<2, 512><<<64, 512, 0, stream>>>(p0, p1, p2, Crpk[2], Czpk[2],
                                             Chpk[2], baseB, outp);
  base_gemm<3><<<64 * 5, 256, 0, stream>>>(outp, Bcat[3], baseB);
  scan_phase<3, 512><<<64, 512, 0, stream>>>(p0, p1, p2, Crpk[3], Czpk[3],
                                             Chpk[3], baseB, outp);
}